// Round 6
// baseline (146.398 us; speedup 1.0000x reference)
//
#include <hip/hip_runtime.h>
#include <math.h>

static constexpr int kB  = 16;
static constexpr int kT  = 15;
static constexpr int kH  = 480;
static constexpr int kW  = 640;
static constexpr int kCH = 16;
static constexpr int kP  = 8;
static constexpr float kEPS = 1e-5f;

__device__ __forceinline__ float gelu_exact(float v) {
    return 0.5f * v * (1.0f + erff(v * 0.7071067811865476f));
}

// ---------------------------------------------------------------------------
// K1: fused downsample + SSM scan + last-step head, split by k-half.
// One block per (b, i, h): reads 15 frames x 30 rows x 320 cols (576 KB,
// coalesced float4), reduces to seq[15][8] in LDS, runs 8 scans
// pole-parallel (64 thr), head channel-parallel (128 thr).
// 512 blocks = 2 blocks/CU, 20 waves/CU for read latency hiding.
// ---------------------------------------------------------------------------
__global__ __launch_bounds__(640) void k_front(
    const float* __restrict__ x,
    const float* __restrict__ w_in, const float* __restrict__ b_in,
    const float* __restrict__ ln1_g, const float* __restrict__ ln1_b,
    const float* __restrict__ Lam_re, const float* __restrict__ Lam_im,
    const float* __restrict__ Bre, const float* __restrict__ Bim,
    const float* __restrict__ Cre, const float* __restrict__ Cim,
    const float* __restrict__ Dv, const float* __restrict__ log_step,
    const float* __restrict__ ln2_g, const float* __restrict__ ln2_b,
    const float* __restrict__ w_enc, const float* __restrict__ w_dec,
    const float* __restrict__ w_out, const float* __restrict__ b_out,
    float* __restrict__ yd)
{
    __shared__ float colsumL[kT * 80];          // [t][col4]
    __shared__ float seqL[kT * 8];              // [t][kk]
    __shared__ float xsr[64], xsi[64];          // [kk][p]
    __shared__ float f2s[128], hgs[128], x2s[128];
    __shared__ float wencT[512], wdecT[256], woutT[256];
    __shared__ float boS[16], dvS[16], g2S[16], b2S[16];
    __shared__ float cav[16], cdv[16], cg1[16], cb1[16], cag[16], cdg[16];
    __shared__ float cLr[8], cLi[8], c1r[8], c1i[8], c0r[8], c0i[8],
                     cbr[8], cbi[8], cmk[8], cst[4];
    __shared__ float cmrT[128], cmiT[128];      // [p][c]

    const int tid = threadIdx.x;
    const int blk = blockIdx.x;                 // (b*16 + i)*2 + h
    const int h   = blk & 1;
    const int bi  = blk >> 1;
    const int i   = bi & 15;
    const int b   = bi >> 4;

    // ---- weight staging (transposed for conflict-free reads) ----
    if (tid < 512) wencT[(tid & 15) * 32 + (tid >> 4)] = w_enc[tid];
    if (tid < 256) {
        int jj = tid >> 4, cc = tid & 15;
        wdecT[tid] = w_dec[cc * 16 + jj];       // wdecT[j*16+c]
        woutT[tid] = w_out[cc * 16 + jj];       // woutT[j*16+c]
    }
    if (tid < 16) {
        boS[tid] = b_out[tid]; dvS[tid] = Dv[tid];
        g2S[tid] = ln2_g[tid]; b2S[tid] = ln2_b[tid];
    }
    // ---- const build step 1 (spare threads) ----
    if (tid >= 544 && tid < 560) {
        int c = tid - 544;
        float mw = 0.f, mb = 0.f;
        #pragma unroll
        for (int k = 0; k < kCH; ++k) { mw += w_in[k]; mb += b_in[k]; }
        mw *= (1.f / kCH); mb *= (1.f / kCH);
        float av = w_in[c] - mw, dv = b_in[c] - mb;
        float g = ln1_g[c], bb = ln1_b[c];
        cav[c] = av; cdv[c] = dv; cg1[c] = g; cb1[c] = bb;
        cag[c] = av * g; cdg[c] = dv * g;
    } else if (tid >= 560 && tid < 568) {
        int p = tid - 560;
        float st  = expf(log_step[p]);
        float lre = Lam_re[p], lim = Lam_im[p];
        float eL  = expf(lre * st);
        cLr[p] = eL * cosf(lim * st);
        cLi[p] = eL * sinf(lim * st);
        float freq = st * fabsf(lim) * 0.15915494309189535f;
        cmk[p] = (freq < 0.25f) ? 1.f : 0.f;
    }
    __syncthreads();
    // ---- const build step 2 ----
    if (tid < 8) {
        int p = tid;
        float lre = Lam_re[p], lim = Lam_im[p];
        float inv = 1.f / (lre * lre + lim * lim);
        float nr = cLr[p] - 1.f, ni = cLi[p];
        float qr = (nr * lre + ni * lim) * inv;
        float qi = (ni * lre - nr * lim) * inv;
        float s1r = 0.f, s1i = 0.f, s0r = 0.f, s0i = 0.f, sbr = 0.f, sbi = 0.f;
        #pragma unroll
        for (int c = 0; c < kCH; ++c) {
            float br = Bre[p * kCH + c], bi2 = Bim[p * kCH + c];
            s1r += cag[c] * br;  s1i += cag[c] * bi2;
            s0r += cdg[c] * br;  s0i += cdg[c] * bi2;
            sbr += cb1[c] * br;  sbi += cb1[c] * bi2;
        }
        c1r[p] = qr * s1r - qi * s1i;  c1i[p] = qr * s1i + qi * s1r;
        c0r[p] = qr * s0r - qi * s0i;  c0i[p] = qr * s0i + qi * s0r;
        cbr[p] = qr * sbr - qi * sbi;  cbi[p] = qr * sbi + qi * sbr;
    } else if (tid == 8) {
        float Saa = 0.f, Sad = 0.f, Sdd = 0.f;
        #pragma unroll
        for (int c = 0; c < kCH; ++c) {
            Saa += cav[c] * cav[c];
            Sad += cav[c] * cdv[c];
            Sdd += cdv[c] * cdv[c];
        }
        cst[0] = Saa * (1.f / kCH);
        cst[1] = Sad * (1.f / kCH);
        cst[2] = Sdd * (1.f / kCH);
    } else if (tid >= 64 && tid < 192) {
        int idx = tid - 64;               // p*16 + c
        int p = idx >> 4, c = idx & 15;
        cmrT[idx] = Cre[c * kP + p] * cmk[p];
        cmiT[idx] = Cim[c * kP + p] * cmk[p];
    }

    // ---- streaming downsample: thread = (fgroup, col4) ----
    const int fgroup = tid / 80;          // frames {fgroup, fgroup+8}
    const int col4   = tid - fgroup * 80; // f4 column within k-half
    const float4* __restrict__ xf4 = (const float4*)x;
    const size_t base0 = ((size_t)(b * kT) * kH + (size_t)i * 30) * 160 + h * 80 + col4;

    float accA = 0.f, accB = 0.f;
    {
        const float4* s0 = xf4 + base0 + (size_t)fgroup * (kH * 160);
        #pragma unroll
        for (int r = 0; r < 30; ++r) {
            float4 v = s0[r * 160];
            accA += (v.x + v.y) + (v.z + v.w);
        }
    }
    if (fgroup < 7) {
        const float4* s0 = xf4 + base0 + (size_t)(fgroup + 8) * (kH * 160);
        #pragma unroll
        for (int r = 0; r < 30; ++r) {
            float4 v = s0[r * 160];
            accB += (v.x + v.y) + (v.z + v.w);
        }
    }
    colsumL[fgroup * 80 + col4] = accA;
    if (fgroup < 7) colsumL[(fgroup + 8) * 80 + col4] = accB;
    __syncthreads();

    // ---- reduce to seq[t][kk]: 120 threads ----
    if (tid < 120) {
        int t = tid / 8, kk = tid & 7;
        float s = 0.f;
        #pragma unroll
        for (int j = 0; j < 10; ++j) s += colsumL[t * 80 + kk * 10 + j];
        seqL[t * 8 + kk] = s * (1.0f / 1200.0f);
    }
    __syncthreads();

    // ---- SSM scan, pole-parallel: thread = (kk, p), 64 threads ----
    if (tid < 64) {
        int kk = tid >> 3, p = tid & 7;
        float Lr = cLr[p], Li = cLi[p];
        float a1r = c1r[p], a1i = c1i[p], a0r = c0r[p], a0i = c0i[p];
        float abr = cbr[p], abi = cbi[p];
        float Saa = cst[0], Sad = cst[1], Sdd = cst[2];
        float xr = 0.f, xi = 0.f;
        #pragma unroll
        for (int t = 0; t < kT; ++t) {
            float s = seqL[t * 8 + kk];
            float r = rsqrtf(s * s * Saa + 2.f * s * Sad + Sdd + kEPS);
            float be = r * s;
            float bur = be * a1r + r * a0r + abr;
            float bui = be * a1i + r * a0i + abi;
            float nr = Lr * xr - Li * xi + bur;
            float ni = Lr * xi + Li * xr + bui;
            xr = nr; xi = ni;
        }
        xsr[kk * 8 + p] = xr; xsi[kk * 8 + p] = xi;
    }
    __syncthreads();

    // ---- head, channel-parallel: thread = (kk, c), 128 threads ----
    if (tid < 128) {
        int kk = tid >> 4, c = tid & 15;
        float s = seqL[14 * 8 + kk];
        float r = rsqrtf(s * s * cst[0] + 2.f * s * cst[1] + cst[2] + kEPS);
        float fx = (s * cav[c] + cdv[c]) * r * cg1[c] + cb1[c];
        float ys = fx * dvS[c];
        #pragma unroll
        for (int p = 0; p < kP; ++p)
            ys += xsr[kk * 8 + p] * cmrT[p * 16 + c] - xsi[kk * 8 + p] * cmiT[p * 16 + c];
        float x1 = gelu_exact(ys) + fx;
        float m = x1;
        m += __shfl_xor(m, 1); m += __shfl_xor(m, 2);
        m += __shfl_xor(m, 4); m += __shfl_xor(m, 8);
        m *= (1.f / kCH);
        float d = x1 - m;
        float v = d * d;
        v += __shfl_xor(v, 1); v += __shfl_xor(v, 2);
        v += __shfl_xor(v, 4); v += __shfl_xor(v, 8);
        v *= (1.f / kCH);
        float rs2 = rsqrtf(v + kEPS);
        f2s[tid] = d * rs2 * g2S[c] + b2S[c];
    }
    __syncthreads();
    if (tid < 128) {
        int kk = tid >> 4, j = tid & 15;
        float e1 = 0.f, e2 = 0.f;
        #pragma unroll
        for (int c = 0; c < kCH; ++c) {
            float f = f2s[kk * 16 + c];
            e1 += f * wencT[c * 32 + j];
            e2 += f * wencT[c * 32 + 16 + j];
        }
        hgs[tid] = e1 * gelu_exact(e2);
    }
    __syncthreads();
    if (tid < 128) {
        int kk = tid >> 4, c = tid & 15;
        float acc = f2s[tid];
        #pragma unroll
        for (int j = 0; j < kCH; ++j) acc += hgs[kk * 16 + j] * wdecT[j * 16 + c];
        x2s[tid] = acc;
    }
    __syncthreads();
    if (tid < 128) {
        int kk = tid >> 4, c = tid & 15;
        float acc = boS[c];
        #pragma unroll
        for (int j = 0; j < kCH; ++j) acc += x2s[kk * 16 + j] * woutT[j * 16 + c];
        yd[(b * kCH + c) * 256 + i * 16 + h * 8 + kk] = acc;
    }
}

// ---------------------------------------------------------------------------
// K2: bilinear upsample 16x16 -> 480x640 per (b,ch). Grid (10 chunks, 256
// images) x 320 threads; per-thread fixed 4-column group, x-weights folded
// once, steady-state loop is pure VALU + coalesced float4 stores (315 MB).
// ---------------------------------------------------------------------------
__global__ __launch_bounds__(320) void k_up(const float* __restrict__ yd,
                                            float* __restrict__ out) {
    const int chunk = blockIdx.x;           // [0,10) -> rows [chunk*48, +48)
    const int bc    = blockIdx.y;           // b*16 + c
    __shared__ float g[256];                // 16x16 source tile
    int tid = threadIdx.x;
    if (tid < 256) g[tid] = yd[bc * 256 + tid];
    __syncthreads();

    const int half = tid / 160;             // 0/1: rows [h0, h0+24)
    const int cw   = tid - half * 160;      // float4 column [0,160)
    const int h0   = chunk * 48 + half * 24;
    const float sy = 15.0f / 479.0f;
    const float sx = 15.0f / 639.0f;

    const int px = cw * 4;
    int xa = (int)((float)px * sx);
    if (xa > 14) xa = 14;
    const int xc2 = min(xa + 2, 15);
    float A[4], Bv[4], Cv[4];
    #pragma unroll
    for (int j = 0; j < 4; ++j) {
        float rx = (float)(px + j) * sx;
        int x0 = (int)rx; if (x0 > 15) x0 = 15;
        float wx = rx - (float)x0;
        int x1 = min(x0 + 1, 15);
        int r0 = x0 - xa;
        int r1 = x1 - xa;
        A[j] = 0.f; Bv[j] = 0.f; Cv[j] = 0.f;
        float w0 = 1.f - wx;
        if (r0 == 0) A[j] += w0; else Bv[j] += w0;
        if (r1 == 1) Bv[j] += wx; else if (r1 == 2) Cv[j] += wx; else A[j] += wx;
    }

    const int ybase = (int)((float)h0 * sy);
    const int ya1 = min(ybase + 1, 15);
    const int ya2 = min(ybase + 2, 15);
    float hr0[4], hr1[4], hr2[4];
    {
        float a0 = g[ybase * 16 + xa], b0 = g[ybase * 16 + xa + 1], c0 = g[ybase * 16 + xc2];
        float a1 = g[ya1   * 16 + xa], b1 = g[ya1   * 16 + xa + 1], c1 = g[ya1   * 16 + xc2];
        float a2 = g[ya2   * 16 + xa], b2 = g[ya2   * 16 + xa + 1], c2 = g[ya2   * 16 + xc2];
        #pragma unroll
        for (int j = 0; j < 4; ++j) {
            hr0[j] = A[j] * a0 + Bv[j] * b0 + Cv[j] * c0;
            hr1[j] = A[j] * a1 + Bv[j] * b1 + Cv[j] * c1;
            hr2[j] = A[j] * a2 + Bv[j] * b2 + Cv[j] * c2;
        }
    }

    float4* dst = (float4*)(out + (size_t)bc * (kH * kW));
    #pragma unroll 4
    for (int r = 0; r < 24; ++r) {
        int ho = h0 + r;
        float ry = (float)ho * sy;
        int y0 = (int)ry;
        float wy = ry - (float)y0;
        bool up = (y0 > ybase);
        float4 res;
        #pragma unroll
        for (int j = 0; j < 4; ++j) {
            float top = up ? hr1[j] : hr0[j];
            float bot = up ? hr2[j] : hr1[j];
            ((float*)&res)[j] = top + (bot - top) * wy;
        }
        dst[ho * 160 + cw] = res;
    }
}

extern "C" void kernel_launch(void* const* d_in, const int* in_sizes, int n_in,
                              void* d_out, int out_size, void* d_ws, size_t ws_size,
                              hipStream_t stream) {
    const float* x     = (const float*)d_in[0];
    const float* w_in  = (const float*)d_in[1];
    const float* b_in  = (const float*)d_in[2];
    const float* ln1_g = (const float*)d_in[3];
    const float* ln1_b = (const float*)d_in[4];
    const float* Lre   = (const float*)d_in[5];
    const float* Lim   = (const float*)d_in[6];
    const float* Bre   = (const float*)d_in[7];
    const float* Bim   = (const float*)d_in[8];
    const float* Cre   = (const float*)d_in[9];
    const float* Cim   = (const float*)d_in[10];
    const float* Dv    = (const float*)d_in[11];
    const float* lstep = (const float*)d_in[12];
    const float* ln2_g = (const float*)d_in[13];
    const float* ln2_b = (const float*)d_in[14];
    const float* w_enc = (const float*)d_in[15];
    const float* w_dec = (const float*)d_in[16];
    const float* w_out = (const float*)d_in[17];
    const float* b_out = (const float*)d_in[18];

    float* yd  = (float*)d_ws;          // kB*kCH*256 = 65536 floats
    float* out = (float*)d_out;

    k_front<<<kB * 16 * 2, 640, 0, stream>>>(x, w_in, b_in, ln1_g, ln1_b, Lre, Lim,
                                             Bre, Bim, Cre, Cim, Dv, lstep, ln2_g,
                                             ln2_b, w_enc, w_dec, w_out, b_out, yd);
    k_up<<<dim3(10, kB * kCH), 320, 0, stream>>>(yd, out);
}